// Round 10
// baseline (80.871 us; speedup 1.0000x reference)
//
#include <hip/hip_runtime.h>
#include <math.h>

#pragma clang fp contract(off)

constexpr int NB  = 16;    // batch
constexpr int NR  = 4096;  // rois per image
constexpr int NC  = 81;    // classes (incl. background)
constexpr int KK  = 200;   // per-class candidate cap == max_total
constexpr int CAP = 4096;  // max kept entries per image
constexpr int SEGCAP = 1024;              // fixed-stride per-(b,c) candidate segment
constexpr int ROWS_PER_BLK = 64;
constexpr int GRID = NB * NR / ROWS_PER_BLK;  // 1024 blocks
constexpr int TCHUNK = 256;               // entries ranked per block in topk
constexpr int NCHUNK = CAP / TCHUNK;      // 16 blocks per image
constexpr float SCORE_TH = 0.5f;
constexpr float IOU_TH   = 0.5f;
constexpr float EPSF     = 1e-8f;

struct Entry {            // 32 bytes
    float s;
    int   cls;
    int   aux;            // roi index (cand) or pre-NMS rank k (final)
    int   pad;
    float y1, x1, y2, x2;
};
static_assert(sizeof(Entry) == 32, "Entry must be 32B");

struct SK { float s; int key; };   // 8B packed (score, cls*KK + prenms_rank)

__device__ __forceinline__ void decode_box(const float4& a, const float4& d,
                                           float& y1, float& x1, float& y2, float& x2) {
    float ah  = a.z - a.x;
    float aw  = a.w - a.y;
    float acy = a.x + 0.5f * ah;
    float acx = a.y + 0.5f * aw;
    float dy = d.x * 0.1f, dx = d.y * 0.1f;
    float dh = d.z * 0.2f, dw = d.w * 0.2f;
    float bh  = expf(dh) * ah;
    float bw  = expf(dw) * aw;
    float bcy = dy * ah + acy;
    float bcx = dx * aw + acx;
    y1 = bcy - 0.5f * bh;
    x1 = bcx - 0.5f * bw;
    y2 = y1 + bh;
    x2 = x1 + bw;
}

// zero counts[NB*NC] + final_count[NB]
__global__ void k_init(int* __restrict__ counts) {
    int i = blockIdx.x * blockDim.x + threadIdx.x;
    if (i < NB * NC + NB) counts[i] = 0;
}

// 4 threads per ROI: LDS-staged coalesced probs, shfl argmax (first-max rule),
// leader decodes box and scatters into fixed-stride (b,c) segment.
__global__ void k_classify(const float* __restrict__ roi,
                           const float* __restrict__ deltas,
                           const float* __restrict__ probs,
                           int* __restrict__ counts,
                           Entry* __restrict__ cand) {
    __shared__ float lp[ROWS_PER_BLK * NC];   // 20736 B
    const float4* src = (const float4*)(probs + (size_t)blockIdx.x * ROWS_PER_BLK * NC);
    float4* dst = (float4*)lp;
    for (int v = threadIdx.x; v < ROWS_PER_BLK * NC / 4; v += blockDim.x) dst[v] = src[v];
    __syncthreads();

    int g = threadIdx.x >> 2;       // row within block
    int j = threadIdx.x & 3;        // sub-lane within row group
    const float* row = lp + g * NC;
    float m = -1.0f;
    int am = 127;
    for (int c = j; c < NC; c += 4) {
        float v = row[c];
        if (v > m) { m = v; am = c; }            // first-max within subset
    }
    for (int mask = 1; mask <= 2; mask <<= 1) {  // tie -> smaller index (jnp.argmax)
        float om = __shfl_xor(m, mask);
        int   oi = __shfl_xor(am, mask);
        if (om > m || (om == m && oi < am)) { m = om; am = oi; }
    }
    if (j != 0) return;
    if (am == 0 || !(m > SCORE_TH)) return;      // background or below threshold

    int r = blockIdx.x * ROWS_PER_BLK + g;
    int b = r / NR;
    float4 a = ((const float4*)roi)[r];
    float4 d = *(const float4*)(deltas + ((size_t)r * NC + am) * 4);
    float y1, x1, y2, x2;
    decode_box(a, d, y1, x1, y2, x2);
    int slot = atomicAdd(&counts[b * NC + am], 1);
    if (slot < SEGCAP) {
        Entry* e = &cand[(size_t)(b * NC + am) * SEGCAP + slot];
        e->s = m; e->cls = am; e->aux = r % NR; e->pad = 0;
        e->y1 = y1; e->x1 = x1; e->y2 = y2; e->x2 = x2;
    }
}

// One block per (image,class): LDS rank -> top-200 -> mask-NMS -> append.
// NMS = (a) parallel build of 256-bit suppression masks sup[i] = {j>i: iou>TH}
//       (all 256 threads, no dependencies), then (b) greedy scan on wave 0
//       with keep-bits in registers (4 bits/lane) — short dependent chain.
__global__ void k_perclass(const int* __restrict__ counts,
                           const Entry* __restrict__ cand,
                           int* __restrict__ final_count,
                           Entry* __restrict__ fin,
                           SK* __restrict__ sk) {
    int b = blockIdx.x / NC, c = blockIdx.x % NC;
    if (c == 0) return;
    int Mc = counts[b * NC + c];
    if (Mc > SEGCAP) Mc = SEGCAP;
    if (Mc == 0) return;
    const Entry* seg = cand + (size_t)(b * NC + c) * SEGCAP;

    __shared__ float ls[SEGCAP], ly1[SEGCAP], lx1[SEGCAP], ly2[SEGCAP], lx2[SEGCAP];
    __shared__ int   lroi[SEGCAP];
    __shared__ float ss[KK], sy1[KK], sx1[KK], sy2[KK], sx2[KK], sar[KK];
    __shared__ unsigned long long sup[KK][4];   // 6.4 KB suppression masks
    __shared__ int   skeep[KK];
    __shared__ int   sbase;

    for (int i = threadIdx.x; i < Mc; i += blockDim.x) {
        Entry e = seg[i];
        ls[i] = e.s; lroi[i] = e.aux;
        ly1[i] = e.y1; lx1[i] = e.x1; ly2[i] = e.y2; lx2[i] = e.x2;
    }
    __syncthreads();

    // stable rank by (score desc, roi asc) — lax.top_k order
    for (int i = threadIdx.x; i < Mc; i += blockDim.x) {
        float si = ls[i]; int ri = lroi[i];
        int rank = 0;
        for (int j = 0; j < Mc; ++j) {
            float sj = ls[j]; int rj = lroi[j];
            rank += (int)((sj > si) | ((sj == si) & (rj < ri)));
        }
        if (rank < KK) {
            ss[rank] = si;
            sy1[rank] = ly1[i]; sx1[rank] = lx1[i];
            sy2[rank] = ly2[i]; sx2[rank] = lx2[i];
            sar[rank] = fmaxf(ly2[i] - ly1[i], 0.f) * fmaxf(lx2[i] - lx1[i], 0.f);
        }
    }
    __syncthreads();

    int L = Mc < KK ? Mc : KK;

    // (a) build suppression masks — fully parallel, no atomics
    for (int idx = threadIdx.x; idx < L * 4; idx += blockDim.x) {
        int i = idx >> 2, w = idx & 3;
        int j0 = w * 64;
        unsigned long long bits = 0;
        int jend = j0 + 64 < L ? j0 + 64 : L;
        int jstart = j0 > i + 1 ? j0 : i + 1;
        if (jstart < jend) {
            float yi1 = sy1[i], xi1 = sx1[i], yi2 = sy2[i], xi2 = sx2[i], ai = sar[i];
            for (int j = jstart; j < jend; ++j) {
                float yy1 = fmaxf(yi1, sy1[j]), xx1 = fmaxf(xi1, sx1[j]);
                float yy2 = fminf(yi2, sy2[j]), xx2 = fminf(xi2, sx2[j]);
                float inter = fmaxf(yy2 - yy1, 0.f) * fmaxf(xx2 - xx1, 0.f);
                float uni = ai + sar[j] - inter;
                if (inter / (uni + EPSF) > IOU_TH) bits |= 1ull << (j - j0);
            }
        }
        sup[i][w] = bits;
    }
    __syncthreads();

    // (b) greedy scan, wave 0: lane l keeps bits for items s*64+l (s=0..3)
    if (threadIdx.x < 64) {
        int lane = threadIdx.x;
        int kmask = 0;
        #pragma unroll
        for (int s = 0; s < 4; ++s) if (s * 64 + lane < L) kmask |= 1 << s;

        for (int i = 0; i < L; ++i) {
            int oi = i & 63, si = i >> 6;
            unsigned long long r0 = sup[i][0], r1 = sup[i][1];
            unsigned long long r2 = sup[i][2], r3 = sup[i][3];
            int keep_i = (__shfl(kmask, oi) >> si) & 1;   // uniform across wave
            if (keep_i) {
                int supb = (int)((r0 >> lane) & 1)
                         | ((int)((r1 >> lane) & 1) << 1)
                         | ((int)((r2 >> lane) & 1) << 2)
                         | ((int)((r3 >> lane) & 1) << 3);
                kmask &= ~supb;
            }
        }
        #pragma unroll
        for (int s = 0; s < 4; ++s) {
            int jj = s * 64 + lane;
            if (jj < L) skeep[jj] = (kmask >> s) & 1;
        }
    }
    __syncthreads();

    // one atomic per block, parallel prefix compaction
    if (threadIdx.x == 0) {
        int tot = 0;
        for (int i = 0; i < L; ++i) tot += skeep[i];
        sbase = atomicAdd(&final_count[b], tot);
    }
    __syncthreads();
    int base = sbase;

    for (int i = threadIdx.x; i < L; i += blockDim.x) {
        if (skeep[i]) {
            int pos = 0;
            for (int j = 0; j < i; ++j) pos += skeep[j];
            int slot = base + pos;
            if (slot < CAP) {
                Entry* fo = &fin[(size_t)b * CAP + slot];
                fo->s = ss[i]; fo->cls = c; fo->aux = i; fo->pad = 0;
                fo->y1 = sy1[i]; fo->x1 = sx1[i]; fo->y2 = sy2[i]; fo->x2 = sx2[i];
                sk[(size_t)b * CAP + slot].s = ss[i];
                sk[(size_t)b * CAP + slot].key = c * KK + i;
            }
        }
    }
}

// NCHUNK blocks per image: thread ranks ONE entry against the LDS-resident
// packed list (ds_read_b128 = 2 entries/instr). Ranks unique & dense -> no race.
__global__ void k_topk(const int* __restrict__ final_count,
                       const Entry* __restrict__ fin,
                       const SK* __restrict__ sk,
                       float* __restrict__ out) {
    int b = blockIdx.x / NCHUNK, chunk = blockIdx.x % NCHUNK;
    int M = final_count[b];
    if (M > CAP) M = CAP;

    float* obox = out + (size_t)b * KK * 4;
    float* olbl = out + (size_t)NB * KK * 4 + (size_t)b * KK;
    float* osc  = out + (size_t)NB * KK * 5 + (size_t)b * KK;

    if (chunk == 0) {   // zero the unwritten tail every call (deterministic output)
        int Mi = M < KK ? M : KK;
        for (int i = Mi + (int)threadIdx.x; i < KK; i += blockDim.x) {
            obox[i * 4 + 0] = 0.f; obox[i * 4 + 1] = 0.f;
            obox[i * 4 + 2] = 0.f; obox[i * 4 + 3] = 0.f;
            olbl[i] = 0.f; osc[i] = 0.f;
        }
    }
    if (chunk * TCHUNK >= M) return;

    __shared__ SK sL[CAP];   // 32 KB packed (score,key)
    const float2* src = (const float2*)(sk + (size_t)b * CAP);
    float2* dstv = (float2*)sL;
    for (int i = threadIdx.x; i < M; i += blockDim.x) dstv[i] = src[i];
    __syncthreads();

    int e = chunk * TCHUNK + threadIdx.x;
    if (e >= M) return;
    float se = sL[e].s; int ke = sL[e].key;
    int rank = 0;
    const float4* p4 = (const float4*)sL;   // 2 SK per float4
    int npair = M >> 1;
    #pragma unroll 4
    for (int p = 0; p < npair; ++p) {
        float4 v = p4[p];
        int k0 = __float_as_int(v.y), k1 = __float_as_int(v.w);
        rank += (int)((v.x > se) | ((v.x == se) & (k0 < ke)));
        rank += (int)((v.z > se) | ((v.z == se) & (k1 < ke)));
    }
    if (M & 1) {
        float sj = sL[M - 1].s; int kj = sL[M - 1].key;
        rank += (int)((sj > se) | ((sj == se) & (kj < ke)));
    }
    if (rank < KK) {
        Entry en = fin[(size_t)b * CAP + e];
        obox[rank * 4 + 0] = fminf(fmaxf(en.y1, 0.f), 1.f);
        obox[rank * 4 + 1] = fminf(fmaxf(en.x1, 0.f), 1.f);
        obox[rank * 4 + 2] = fminf(fmaxf(en.y2, 0.f), 1.f);
        obox[rank * 4 + 3] = fminf(fmaxf(en.x2, 0.f), 1.f);
        olbl[rank] = (float)en.cls;
        osc[rank]  = en.s;
    }
}

extern "C" void kernel_launch(void* const* d_in, const int* in_sizes, int n_in,
                              void* d_out, int out_size, void* d_ws, size_t ws_size,
                              hipStream_t stream) {
    const float* roi    = (const float*)d_in[0];
    const float* deltas = (const float*)d_in[1];
    const float* probs  = (const float*)d_in[2];
    float* out = (float*)d_out;

    int* ws_i        = (int*)d_ws;
    int* counts      = ws_i;                 // NB*NC ints
    int* final_count = ws_i + NB * NC;       // NB ints (contiguous with counts)
    Entry* cand = (Entry*)((char*)d_ws + 16384);              // NB*NC*SEGCAP*32B = 42.5MB
    Entry* fin  = cand + (size_t)NB * NC * SEGCAP;            // 2MB
    SK*    sk   = (SK*)(fin + (size_t)NB * CAP);              // 512KB

    k_init<<<(NB * NC + NB + 255) / 256, 256, 0, stream>>>(counts);
    k_classify<<<GRID, 256, 0, stream>>>(roi, deltas, probs, counts, cand);
    k_perclass<<<NB * NC, 256, 0, stream>>>(counts, cand, final_count, fin, sk);
    k_topk<<<NB * NCHUNK, 256, 0, stream>>>(final_count, fin, sk, out);
}

// Round 11
// 72.367 us; speedup vs baseline: 1.1175x; 1.1175x over previous
//
#include <hip/hip_runtime.h>
#include <math.h>

#pragma clang fp contract(off)

constexpr int NB  = 16;    // batch
constexpr int NR  = 4096;  // rois per image
constexpr int NC  = 81;    // classes (incl. background)
constexpr int KK  = 200;   // per-class candidate cap == max_total
constexpr int CAP = 4096;  // max kept entries per image
constexpr int ROWS_PER_BLK = 64;
constexpr int CHUNKS = NR / ROWS_PER_BLK;     // 64 chunks per image
constexpr int GRID = NB * NR / ROWS_PER_BLK;  // 1024 blocks
constexpr int MAXC = 1024;                    // per-class LDS candidate cap
constexpr int TCHUNK = 256;
constexpr int NCHUNK = CAP / TCHUNK;          // 16 blocks per image
constexpr float SCORE_TH = 0.5f;
constexpr float IOU_TH   = 0.5f;
constexpr float EPSF     = 1e-8f;

struct SK { float s; int key; };   // 8B packed (score, cls*KK + prenms_rank)

__device__ __forceinline__ void decode_box(const float4& a, const float4& d,
                                           float& y1, float& x1, float& y2, float& x2) {
    float ah  = a.z - a.x;
    float aw  = a.w - a.y;
    float acy = a.x + 0.5f * ah;
    float acx = a.y + 0.5f * aw;
    float dy = d.x * 0.1f, dx = d.y * 0.1f;
    float dh = d.z * 0.2f, dw = d.w * 0.2f;
    float bh  = expf(dh) * ah;
    float bw  = expf(dw) * aw;
    float bcy = dy * ah + acy;
    float bcx = dx * aw + acx;
    y1 = bcy - 0.5f * bh;
    x1 = bcx - 0.5f * bw;
    y2 = y1 + bh;
    x2 = x1 + bw;
}

// 4 threads/ROI, 64 ROIs/block. Ballot-compaction into per-block fixed slots:
// blk_cnt[bid] written unconditionally -> no init kernel, no global atomics.
// Chunk-0 blocks also zero final_count[b] (consumed only by later kernels).
__global__ void k_classify(const float* __restrict__ roi,
                           const float* __restrict__ deltas,
                           const float* __restrict__ probs,
                           int* __restrict__ blk_cnt,
                           int* __restrict__ final_count,
                           int* __restrict__ scls,
                           float2* __restrict__ ssr,
                           float4* __restrict__ sbox) {
    __shared__ float lp[ROWS_PER_BLK * NC];   // 20736 B
    __shared__ int wcnt[4], wbase[4];
    const int bid = blockIdx.x, tid = threadIdx.x;

    const float4* src = (const float4*)(probs + (size_t)bid * ROWS_PER_BLK * NC);
    float4* dst = (float4*)lp;
    for (int v = tid; v < ROWS_PER_BLK * NC / 4; v += 256) dst[v] = src[v];
    __syncthreads();

    int g = tid >> 2;               // row within block
    int j = tid & 3;                // sub-lane within row group
    const float* row = lp + g * NC;
    float m = -1.0f;
    int am = 127;
    for (int c = j; c < NC; c += 4) {
        float v = row[c];
        if (v > m) { m = v; am = c; }            // first-max within subset
    }
    for (int mask = 1; mask <= 2; mask <<= 1) {  // butterfly: all 4 get result
        float om = __shfl_xor(m, mask);
        int   oi = __shfl_xor(am, mask);
        if (om > m || (om == m && oi < am)) { m = om; am = oi; }
    }

    bool pred = (j == 0) && (am != 0) && (m > SCORE_TH);
    unsigned long long bal = __ballot(pred);
    int lane = tid & 63, w = tid >> 6;
    if (lane == 0) wcnt[w] = __popcll(bal);
    __syncthreads();
    if (tid == 0) {
        int run = 0;
        for (int i = 0; i < 4; ++i) { wbase[i] = run; run += wcnt[i]; }
        blk_cnt[bid] = run;
        if ((bid & (CHUNKS - 1)) == 0) final_count[bid / CHUNKS] = 0;
    }
    __syncthreads();

    if (pred) {
        int pos = wbase[w] + __popcll(bal & ((1ull << lane) - 1ull));
        int r = bid * ROWS_PER_BLK + g;
        float4 a = ((const float4*)roi)[r];
        float4 d = *(const float4*)(deltas + ((size_t)r * NC + am) * 4);
        float y1, x1, y2, x2;
        decode_box(a, d, y1, x1, y2, x2);
        int idx = bid * ROWS_PER_BLK + pos;      // == b*NR + chunk*64 + pos
        scls[idx] = am;
        ssr[idx]  = make_float2(m, (float)(r & (NR - 1)));   // exact: r%NR < 2^24
        sbox[idx] = make_float4(y1, x1, y2, x2);
    }
}

// One block per (image,class): gather class-c candidates via scls scan ->
// LDS stable rank -> top-200 -> parallel mask build -> wave-0 greedy NMS ->
// aggregated append to fbox/sk.
__global__ void k_perclass(const int* __restrict__ blk_cnt,
                           const int* __restrict__ scls,
                           const float2* __restrict__ ssr,
                           const float4* __restrict__ sbox,
                           int* __restrict__ final_count,
                           float4* __restrict__ fbox,
                           SK* __restrict__ sk) {
    __shared__ int ccnt[CHUNKS];
    __shared__ int lcnt;
    __shared__ float ls[MAXC], lroi[MAXC];
    __shared__ unsigned short lidx[MAXC];
    __shared__ float ss[KK], sy1[KK], sx1[KK], sy2[KK], sx2[KK], sar[KK];
    __shared__ unsigned long long sup[KK][4];
    __shared__ int skeep[KK];
    __shared__ int sbase;

    int b = blockIdx.x / NC, c = blockIdx.x % NC;
    if (c == 0) return;
    const int tid = threadIdx.x;

    if (tid < CHUNKS) ccnt[tid] = blk_cnt[b * CHUNKS + tid];
    if (tid == 0) lcnt = 0;
    __syncthreads();

    const int* sc = scls + (size_t)b * NR;
    const float2* sr = ssr + (size_t)b * NR;
    for (int sidx = tid; sidx < NR; sidx += 256) {
        int chunk = sidx >> 6, s = sidx & 63;
        if (s < ccnt[chunk] && sc[sidx] == c) {
            int p = atomicAdd(&lcnt, 1);         // LDS atomic; order-free keys
            if (p < MAXC) {
                float2 v = sr[sidx];
                ls[p] = v.x; lroi[p] = v.y; lidx[p] = (unsigned short)sidx;
            }
        }
    }
    __syncthreads();
    int Mc = lcnt; if (Mc > MAXC) Mc = MAXC;
    if (Mc == 0) return;

    // stable rank by (score desc, roi asc) — lax.top_k order
    for (int i = tid; i < Mc; i += 256) {
        float si = ls[i], ri = lroi[i];
        int rank = 0;
        for (int jj = 0; jj < Mc; ++jj) {
            float sj = ls[jj], rj = lroi[jj];
            rank += (int)((sj > si) | ((sj == si) & (rj < ri)));
        }
        if (rank < KK) {
            float4 bx = sbox[(size_t)b * NR + lidx[i]];
            ss[rank] = si;
            sy1[rank] = bx.x; sx1[rank] = bx.y; sy2[rank] = bx.z; sx2[rank] = bx.w;
            sar[rank] = fmaxf(bx.z - bx.x, 0.f) * fmaxf(bx.w - bx.y, 0.f);
        }
    }
    __syncthreads();

    int L = Mc < KK ? Mc : KK;

    // parallel suppression-mask build: sup[i] = {j>i : IoU(i,j) > TH}
    for (int idx = tid; idx < L * 4; idx += 256) {
        int i = idx >> 2, w = idx & 3;
        int j0 = w * 64;
        unsigned long long bits = 0;
        int jend = j0 + 64 < L ? j0 + 64 : L;
        int jstart = j0 > i + 1 ? j0 : i + 1;
        if (jstart < jend) {
            float yi1 = sy1[i], xi1 = sx1[i], yi2 = sy2[i], xi2 = sx2[i], ai = sar[i];
            for (int j = jstart; j < jend; ++j) {
                float yy1 = fmaxf(yi1, sy1[j]), xx1 = fmaxf(xi1, sx1[j]);
                float yy2 = fminf(yi2, sy2[j]), xx2 = fminf(xi2, sx2[j]);
                float inter = fmaxf(yy2 - yy1, 0.f) * fmaxf(xx2 - xx1, 0.f);
                float uni = ai + sar[j] - inter;
                if (inter / (uni + EPSF) > IOU_TH) bits |= 1ull << (j - j0);
            }
        }
        sup[i][w] = bits;
    }
    __syncthreads();

    // greedy scan on wave 0: keep-bits in registers (4 bits/lane)
    if (tid < 64) {
        int lane = tid;
        int kmask = 0;
        #pragma unroll
        for (int s = 0; s < 4; ++s) if (s * 64 + lane < L) kmask |= 1 << s;
        for (int i = 0; i < L; ++i) {
            int oi = i & 63, si = i >> 6;
            unsigned long long r0 = sup[i][0], r1 = sup[i][1];
            unsigned long long r2 = sup[i][2], r3 = sup[i][3];
            int keep_i = (__shfl(kmask, oi) >> si) & 1;   // uniform across wave
            if (keep_i) {
                int supb = (int)((r0 >> lane) & 1)
                         | ((int)((r1 >> lane) & 1) << 1)
                         | ((int)((r2 >> lane) & 1) << 2)
                         | ((int)((r3 >> lane) & 1) << 3);
                kmask &= ~supb;
            }
        }
        #pragma unroll
        for (int s = 0; s < 4; ++s) {
            int jj = s * 64 + lane;
            if (jj < L) skeep[jj] = (kmask >> s) & 1;
        }
    }
    __syncthreads();

    if (tid == 0) {
        int tot = 0;
        for (int i = 0; i < L; ++i) tot += skeep[i];
        sbase = atomicAdd(&final_count[b], tot);
    }
    __syncthreads();
    int base = sbase;

    for (int i = tid; i < L; i += 256) {
        if (skeep[i]) {
            int pos = 0;
            for (int j = 0; j < i; ++j) pos += skeep[j];
            int slot = base + pos;
            if (slot < CAP) {
                fbox[(size_t)b * CAP + slot] = make_float4(sy1[i], sx1[i], sy2[i], sx2[i]);
                sk[(size_t)b * CAP + slot].s = ss[i];
                sk[(size_t)b * CAP + slot].key = c * KK + i;
            }
        }
    }
}

// NCHUNK blocks per image: thread ranks ONE entry against the LDS-resident
// packed list (float4 = 2 entries/read). Ranks unique & dense -> no race.
__global__ void k_topk(const int* __restrict__ final_count,
                       const float4* __restrict__ fbox,
                       const SK* __restrict__ sk,
                       float* __restrict__ out) {
    int b = blockIdx.x / NCHUNK, chunk = blockIdx.x % NCHUNK;
    int M = final_count[b];
    if (M > CAP) M = CAP;

    float* obox = out + (size_t)b * KK * 4;
    float* olbl = out + (size_t)NB * KK * 4 + (size_t)b * KK;
    float* osc  = out + (size_t)NB * KK * 5 + (size_t)b * KK;

    if (chunk == 0) {   // zero the unwritten tail every call (deterministic output)
        int Mi = M < KK ? M : KK;
        for (int i = Mi + (int)threadIdx.x; i < KK; i += blockDim.x) {
            obox[i * 4 + 0] = 0.f; obox[i * 4 + 1] = 0.f;
            obox[i * 4 + 2] = 0.f; obox[i * 4 + 3] = 0.f;
            olbl[i] = 0.f; osc[i] = 0.f;
        }
    }
    if (chunk * TCHUNK >= M) return;

    __shared__ SK sL[CAP];   // 32 KB packed (score,key)
    const float2* src = (const float2*)(sk + (size_t)b * CAP);
    float2* dstv = (float2*)sL;
    for (int i = threadIdx.x; i < M; i += blockDim.x) dstv[i] = src[i];
    __syncthreads();

    int e = chunk * TCHUNK + threadIdx.x;
    if (e >= M) return;
    float se = sL[e].s; int ke = sL[e].key;
    int rank = 0;
    const float4* p4 = (const float4*)sL;   // 2 SK per float4
    int npair = M >> 1;
    #pragma unroll 4
    for (int p = 0; p < npair; ++p) {
        float4 v = p4[p];
        int k0 = __float_as_int(v.y), k1 = __float_as_int(v.w);
        rank += (int)((v.x > se) | ((v.x == se) & (k0 < ke)));
        rank += (int)((v.z > se) | ((v.z == se) & (k1 < ke)));
    }
    if (M & 1) {
        float sj = sL[M - 1].s; int kj = sL[M - 1].key;
        rank += (int)((sj > se) | ((sj == se) & (kj < ke)));
    }
    if (rank < KK) {
        float4 bx = fbox[(size_t)b * CAP + e];
        obox[rank * 4 + 0] = fminf(fmaxf(bx.x, 0.f), 1.f);
        obox[rank * 4 + 1] = fminf(fmaxf(bx.y, 0.f), 1.f);
        obox[rank * 4 + 2] = fminf(fmaxf(bx.z, 0.f), 1.f);
        obox[rank * 4 + 3] = fminf(fmaxf(bx.w, 0.f), 1.f);
        olbl[rank] = (float)(ke / KK);
        osc[rank]  = se;
    }
}

extern "C" void kernel_launch(void* const* d_in, const int* in_sizes, int n_in,
                              void* d_out, int out_size, void* d_ws, size_t ws_size,
                              hipStream_t stream) {
    const float* roi    = (const float*)d_in[0];
    const float* deltas = (const float*)d_in[1];
    const float* probs  = (const float*)d_in[2];
    float* out = (float*)d_out;

    char* base = (char*)d_ws;
    int*    blk_cnt     = (int*)base;                          // 1024 ints = 4 KB
    int*    final_count = (int*)(base + 4096);                 // 16 ints
    int*    scls        = (int*)(base + 8192);                 // 256 KB
    float2* ssr         = (float2*)(base + 8192 + 262144);     // 512 KB
    float4* sbox        = (float4*)(base + 8192 + 262144 + 524288);            // 1 MB
    float4* fbox        = (float4*)(base + 8192 + 262144 + 524288 + 1048576);  // 1 MB
    SK*     sk          = (SK*)(base + 8192 + 262144 + 524288 + 1048576 + 1048576); // 512 KB

    k_classify<<<GRID, 256, 0, stream>>>(roi, deltas, probs, blk_cnt, final_count,
                                         scls, ssr, sbox);
    k_perclass<<<NB * NC, 256, 0, stream>>>(blk_cnt, scls, ssr, sbox,
                                            final_count, fbox, sk);
    k_topk<<<NB * NCHUNK, 256, 0, stream>>>(final_count, fbox, sk, out);
}